// Round 6
// baseline (401.105 us; speedup 1.0000x reference)
//
#include <hip/hip_runtime.h>

// Problem: B=256, N=1000, D=128, H=8, dk=16. grid=256 (one block per b) —
// 1 block/CU, occupancy == waves/block (1024 thr = 16 waves). Single fused
// kernel; qkp/glp live in LDS.
//
// R6: phase C 6->3 barriers/tile (reg-prefetch next E tile, wave0 shfl
// reductions for m/l, inline exp in Ebar accumulate); phase E tile loop
// barrier-free via 8-lane shfl butterfly.
//
// Math:
//   qkp[h,c]  = 0.25 * sum_e W_node[c, h*16+e] * q[h*16+e]
//   compat[h,n] = sum_c E[n,c] * qkp[h,c]            (masked -> -1e9)
//   Ebar[h,c] = sum_n softmax_n(compat)[h,n] * E[n,c] (online softmax)
//   heads -> glimpse -> gp[c] = (1/sqrt(128)) sum_d W_node[c,256+d]*glimpse[d]
//   logits[n] = sum_c E[n,c] * gp[c]; z=10*tanh; mask; log_softmax.

#define NEG (-1e9f)

__global__ __launch_bounds__(1024) void k_fused(
    const float* __restrict__ E, const float* __restrict__ Wn,
    const float* __restrict__ Wf, const float* __restrict__ Ws,
    const float* __restrict__ Wo,
    const int* __restrict__ fi, const int* __restrict__ li,
    const int* __restrict__ maskI, const unsigned char* __restrict__ maskB,
    float* __restrict__ out)
{
    const int b = blockIdx.x;
    const int t = threadIdx.x;

    __shared__ float4 Et[4096];      // 64 KB: mean scratch / E tile / Ebar reduce
    __shared__ float4 qk4[256];      // qkp, float4-slot swizzle s^(s>>2)
    __shared__ float4 pt4[256];      // z[] staging for phase E softmax
    __shared__ float4 EbarF4[256];
    __shared__ float4 mu4[32], e14[32], e24[32], gp4[32];
    __shared__ float q[128], heads[128], gl[128];
    __shared__ float qred[8][128];
    __shared__ float ct[128 * 9];    // compat [row][h] pad 9
    __shared__ float mh[8], lh[8], al[8];
    __shared__ float red[16];
    __shared__ float stat[2];
    __shared__ int flagS;

    float* const mu = (float*)mu4;
    float* const e1 = (float*)e14;
    float* const e2 = (float*)e24;
    float* const gp = (float*)gp4;
    float* const pt = (float*)pt4;
    float* const EbarF = (float*)EbarF4;
    float* const qkf = (float*)qk4;

    const float4* E4 = (const float4*)(E + (size_t)b * 128000);

    if (t == 0) flagS = 0;
    // mask-format probe: int32 upload => every word 0/1 => upper 3 bytes zero.
    const uint4 dv = ((const uint4*)maskI)[t];           // first 16 KB
    const unsigned det = (dv.x | dv.y | dv.z | dv.w) & 0xFFFFFF00u;

    const int rr = t >> 3, qq = t & 7;    // phase C/E: 128 rows x 8 octants
    const int c4 = t & 31, sl = t >> 5;   // Ebar: 32 slices x 4 rows

    // Early-issue the phase-C tile-0 prefetch (rows 0..127 — also warms L2
    // for phase A). Held in regs across phases A/B.
    float4 vcur[4];
    #pragma unroll
    for (int i = 0; i < 4; ++i) vcur[i] = E4[rr * 32 + qq * 4 + i];

    // ---- Phase A: graph mean (scratch := Et), first/last embeddings ----
    {
        const int cm = t & 31, sm = t >> 5;
        float4 acc = make_float4(0.f, 0.f, 0.f, 0.f);
        for (int r = sm; r < 1000; r += 32) {
            const float4 v = E4[r * 32 + cm];
            acc.x += v.x; acc.y += v.y; acc.z += v.z; acc.w += v.w;
        }
        Et[t] = acc;
    }
    if (t >= 512 && t < 544) {
        e14[t - 512] = E4[fi[b] * 32 + (t - 512)];
    } else if (t >= 544 && t < 576) {
        e24[t - 544] = E4[li[b] * 32 + (t - 544)];
    }
    __syncthreads();
    if (det) atomicOr(&flagS, 1);
    if (t < 32) {
        float4 acc = Et[t];
        #pragma unroll
        for (int s = 1; s < 32; ++s) {
            const float4 v = Et[s * 32 + t];
            acc.x += v.x; acc.y += v.y; acc.z += v.z; acc.w += v.w;
        }
        const float inv = 1.0f / 1000.0f;
        mu4[t] = make_float4(acc.x * inv, acc.y * inv, acc.z * inv, acc.w * inv);
    }
    __syncthreads();

    // ---- Phase B: q = mu@Wf + e1@Ws[0:128] + e2@Ws[128:256], 8-way k-split ----
    {
        const int part = t >> 7, d = t & 127;
        float acc = 0.f;
        const int k0 = part * 48;
        for (int k = k0; k < k0 + 48; ++k) {
            const float s = (k < 128) ? mu[k] : (k < 256 ? e1[k - 128] : e2[k - 256]);
            const float w = (k < 128) ? Wf[k * 128 + d] : Ws[(k - 128) * 128 + d];
            acc += s * w;
        }
        qred[part][d] = acc;
    }
    __syncthreads();
    if (t < 128) {
        float acc = 0.f;
        #pragma unroll
        for (int p = 0; p < 8; ++p) acc += qred[p][t];
        q[t] = acc;
    }
    __syncthreads();
    // qkp[h][c] -> qk4 (LDS only), slot-swizzled s^(s>>2)
    {
        const int j = t & 127, cg = t >> 7;
        const float qj = q[j];
        for (int c0 = 0; c0 < 128; c0 += 8) {
            const int c = c0 + cg;
            float v = Wn[c * 384 + j] * qj;
            v += __shfl_down(v, 8, 16);
            v += __shfl_down(v, 4, 16);
            v += __shfl_down(v, 2, 16);
            v += __shfl_down(v, 1, 16);
            if ((j & 15) == 0) {
                const int h = j >> 4, s = c >> 2;
                qkf[h * 128 + (s ^ (s >> 2)) * 4 + (c & 3)] = v * 0.25f;
            }
        }
    }
    if (t < 8) { mh[t] = -3e38f; lh[t] = 0.f; }
    __syncthreads();

    const bool useB = (flagS != 0);

    // ---- Phase C: online-softmax glimpse attention, 8 tiles x 128 rows ----
    // Per tile: [stage+compat+prefetch] B1 [wave0: m,al] B2 [Ebar inline-exp
    //           + wave0: l] B3(loop top)
    float4 eacc[8];
    #pragma unroll
    for (int h = 0; h < 8; ++h) eacc[h] = make_float4(0.f, 0.f, 0.f, 0.f);

    for (int tile = 0; tile < 8; ++tile) {
        // prefetch next tile (in flight across all three barriers)
        float4 vnext[4];
        if (tile < 7) {
            const int gn = (tile + 1) * 128 + rr;
            if (gn < 1000) {
                #pragma unroll
                for (int i = 0; i < 4; ++i) vnext[i] = E4[gn * 32 + qq * 4 + i];
            } else {
                #pragma unroll
                for (int i = 0; i < 4; ++i) vnext[i] = make_float4(0.f, 0.f, 0.f, 0.f);
            }
        }
        // stage + compat partials + 8-lane butterfly
        {
            const int g = tile * 128 + rr;
            float pch[8];
            #pragma unroll
            for (int h = 0; h < 8; ++h) pch[h] = 0.f;
            #pragma unroll
            for (int i = 0; i < 4; ++i) {
                const int grp = qq * 4 + i;
                Et[rr * 32 + (grp ^ (rr & 7))] = vcur[i];
                const int sg = grp ^ (grp >> 2);
                #pragma unroll
                for (int h = 0; h < 8; ++h) {
                    const float4 w = qk4[h * 32 + sg];
                    pch[h] += vcur[i].x * w.x + vcur[i].y * w.y + vcur[i].z * w.z + vcur[i].w * w.w;
                }
            }
            #pragma unroll
            for (int m = 1; m <= 4; m <<= 1) {
                #pragma unroll
                for (int h = 0; h < 8; ++h) pch[h] += __shfl_xor(pch[h], m, 64);
            }
            bool msk = (g >= 1000);
            if (!msk) msk = useB ? (maskB[b * 1000 + g] != 0)
                                 : (maskI[b * 1000 + g] != 0);
            ct[rr * 9 + qq] = msk ? NEG : pch[qq];
        }
        __syncthreads();
        // wave0: per-head running max via 8-lane shfl groups
        if (t < 64) {
            const int h = t >> 3, j = t & 7;
            float mt = -3e38f;
            for (int r = j; r < 128; r += 8) mt = fmaxf(mt, ct[r * 9 + h]);
            mt = fmaxf(mt, __shfl_xor(mt, 1, 64));
            mt = fmaxf(mt, __shfl_xor(mt, 2, 64));
            mt = fmaxf(mt, __shfl_xor(mt, 4, 64));
            if (j == 0) {
                const float mnew = fmaxf(mh[h], mt);
                al[h] = __expf(mh[h] - mnew);
                mh[h] = mnew;
            }
        }
        __syncthreads();
        // Ebar accumulate with inline exp (4 rows/thread); wave0 also does l
        {
            float alr[8], mhr[8];
            #pragma unroll
            for (int h = 0; h < 8; ++h) { alr[h] = al[h]; mhr[h] = mh[h]; }
            #pragma unroll
            for (int h = 0; h < 8; ++h) {
                eacc[h].x *= alr[h]; eacc[h].y *= alr[h];
                eacc[h].z *= alr[h]; eacc[h].w *= alr[h];
            }
            #pragma unroll
            for (int j2 = 0; j2 < 4; ++j2) {
                const int r = sl * 4 + j2;
                const float4 ev = Et[r * 32 + (c4 ^ (r & 7))];
                float p[8];
                #pragma unroll
                for (int h = 0; h < 8; ++h) p[h] = __expf(ct[r * 9 + h] - mhr[h]);
                #pragma unroll
                for (int h = 0; h < 8; ++h) {
                    eacc[h].x += p[h] * ev.x; eacc[h].y += p[h] * ev.y;
                    eacc[h].z += p[h] * ev.z; eacc[h].w += p[h] * ev.w;
                }
            }
        }
        if (t < 64) {
            const int h = t >> 3, j = t & 7;
            const float mhh = mh[h];
            float s = 0.f;
            for (int r = j; r < 128; r += 8) s += __expf(ct[r * 9 + h] - mhh);
            s += __shfl_xor(s, 1, 64);
            s += __shfl_xor(s, 2, 64);
            s += __shfl_xor(s, 4, 64);
            if (j == 0) lh[h] = lh[h] * al[h] + s;
        }
        if (tile < 7) {
            #pragma unroll
            for (int i = 0; i < 4; ++i) vcur[i] = vnext[i];
        }
        __syncthreads();
    }

    // ---- reduce 32 slice-partials in two stages (Et holds 16 slices) ----
    if (sl >= 16) {
        #pragma unroll
        for (int h = 0; h < 8; ++h) Et[(sl - 16) * 256 + h * 32 + c4] = eacc[h];
    }
    __syncthreads();
    if (sl < 16) {
        #pragma unroll
        for (int h = 0; h < 8; ++h) {
            const float4 o = Et[sl * 256 + h * 32 + c4];
            eacc[h].x += o.x; eacc[h].y += o.y; eacc[h].z += o.z; eacc[h].w += o.w;
            Et[sl * 256 + h * 32 + c4] = eacc[h];
        }
    }
    __syncthreads();
    if (t < 256) {
        const int h = t >> 5, cc = t & 31;
        float4 s = make_float4(0.f, 0.f, 0.f, 0.f);
        #pragma unroll
        for (int s2 = 0; s2 < 16; ++s2) {
            const float4 v = Et[s2 * 256 + h * 32 + cc];
            s.x += v.x; s.y += v.y; s.z += v.z; s.w += v.w;
        }
        const float invl = 1.0f / lh[h];
        EbarF4[h * 32 + cc] = make_float4(s.x * invl, s.y * invl, s.z * invl, s.w * invl);
    }
    __syncthreads();

    // ---- Phase D: heads -> glimpse -> gp, 8-way k-split each ----
    {
        const int part = t >> 7, d = t & 127, h = d >> 4;
        float acc = 0.f;
        const int c0 = part * 16;
        for (int c = c0; c < c0 + 16; ++c) acc += EbarF[h * 128 + c] * Wn[c * 384 + 128 + d];
        qred[part][d] = acc;
    }
    __syncthreads();
    if (t < 128) {
        float acc = 0.f;
        #pragma unroll
        for (int p = 0; p < 8; ++p) acc += qred[p][t];
        heads[t] = acc;
    }
    __syncthreads();
    {
        const int part = t >> 7, d = t & 127;
        float acc = 0.f;
        const int j0 = part * 16;
        for (int j = j0; j < j0 + 16; ++j) acc += heads[j] * Wo[j * 128 + d];
        qred[part][d] = acc;
    }
    __syncthreads();
    if (t < 128) {
        float acc = 0.f;
        #pragma unroll
        for (int p = 0; p < 8; ++p) acc += qred[p][t];
        gl[t] = acc;
    }
    __syncthreads();
    {
        const int part = t >> 7, c = t & 127;
        float acc = 0.f;
        const int d0 = part * 16;
        for (int d = d0; d < d0 + 16; ++d) acc += Wn[c * 384 + 256 + d] * gl[d];
        qred[part][c] = acc;
    }
    __syncthreads();
    if (t < 128) {
        float acc = 0.f;
        #pragma unroll
        for (int p = 0; p < 8; ++p) acc += qred[p][t];
        gp[t] = acc * 0.08838834764831845f;   // 1/sqrt(128)
    }
    __syncthreads();

    // ---- Phase E: logits via shfl butterfly — no barriers in tile loop ----
    for (int tile = 0; tile < 8; ++tile) {
        const int g = tile * 128 + rr;
        float acc = 0.f;
        if (g < 1000) {
            #pragma unroll
            for (int i = 0; i < 4; ++i) {
                const float4 v = E4[g * 32 + qq * 4 + i];
                const float4 w = gp4[qq * 4 + i];
                acc += v.x * w.x + v.y * w.y + v.z * w.z + v.w * w.w;
            }
        }
        acc += __shfl_xor(acc, 1, 64);
        acc += __shfl_xor(acc, 2, 64);
        acc += __shfl_xor(acc, 4, 64);
        if (qq == 0 && g < 1000) {
            float zz = 10.0f * tanhf(acc);
            const bool m = useB ? (maskB[b * 1000 + g] != 0)
                                : (maskI[b * 1000 + g] != 0);
            if (m) zz = NEG;
            pt[g] = zz;
        }
    }
    __syncthreads();
    float v = (t < 1000) ? pt[t] : -3e38f;
    #pragma unroll
    for (int off = 32; off > 0; off >>= 1) v = fmaxf(v, __shfl_down(v, off, 64));
    if ((t & 63) == 0) red[t >> 6] = v;
    __syncthreads();
    if (t == 0) {
        float m = red[0];
        for (int i = 1; i < 16; ++i) m = fmaxf(m, red[i]);
        stat[0] = m;
    }
    __syncthreads();
    float sv = (t < 1000) ? __expf(pt[t] - stat[0]) : 0.f;
    #pragma unroll
    for (int off = 32; off > 0; off >>= 1) sv += __shfl_down(sv, off, 64);
    if ((t & 63) == 0) red[t >> 6] = sv;
    __syncthreads();
    if (t == 0) {
        float s = 0.f;
        for (int i = 0; i < 16; ++i) s += red[i];
        stat[1] = stat[0] + __logf(s);
    }
    __syncthreads();
    if (t < 1000)
        out[(size_t)b * 1000 + t] = pt[t] - stat[1];
}

// ---------------------------------------------------------------------------
extern "C" void kernel_launch(void* const* d_in, const int* in_sizes, int n_in,
                              void* d_out, int out_size, void* d_ws, size_t ws_size,
                              hipStream_t stream) {
    const float* E  = (const float*)d_in[0];
    const float* Wn = (const float*)d_in[1];
    const float* Wf = (const float*)d_in[2];
    const float* Ws = (const float*)d_in[3];
    const float* Wo = (const float*)d_in[4];
    const int*   fi = (const int*)d_in[5];
    const int*   li = (const int*)d_in[6];
    const int*   maskI = (const int*)d_in[7];
    const unsigned char* maskB = (const unsigned char*)d_in[7];
    float* out = (float*)d_out;

    k_fused<<<256, 1024, 0, stream>>>(E, Wn, Wf, Ws, Wo, fi, li, maskI, maskB, out);
}

// Round 7
// 395.283 us; speedup vs baseline: 1.0147x; 1.0147x over previous
//
#include <hip/hip_runtime.h>

// Problem: B=256, N=1000, D=128, H=8, dk=16. grid=256 (one block per b) —
// 1 block/CU, occupancy == waves/block (1024 thr = 16 waves = 4 waves/EU).
//
// R7: __launch_bounds__(1024, 4) — R6 regressed because the default VGPR cap
// (64, for 8 waves/EU) spilled the tile prefetch to scratch (WRITE_SIZE
// 3 MB -> 413 MB). 4 waves/EU permits 128 VGPRs; eacc(32)+vcur(16)+vnext(16)
// now live in registers. Structure otherwise identical to R6.
//
// Math:
//   qkp[h,c]  = 0.25 * sum_e W_node[c, h*16+e] * q[h*16+e]
//   compat[h,n] = sum_c E[n,c] * qkp[h,c]            (masked -> -1e9)
//   Ebar[h,c] = sum_n softmax_n(compat)[h,n] * E[n,c] (online softmax)
//   heads -> glimpse -> gp[c] = (1/sqrt(128)) sum_d W_node[c,256+d]*glimpse[d]
//   logits[n] = sum_c E[n,c] * gp[c]; z=10*tanh; mask; log_softmax.

#define NEG (-1e9f)

__global__ __launch_bounds__(1024, 4) void k_fused(
    const float* __restrict__ E, const float* __restrict__ Wn,
    const float* __restrict__ Wf, const float* __restrict__ Ws,
    const float* __restrict__ Wo,
    const int* __restrict__ fi, const int* __restrict__ li,
    const int* __restrict__ maskI, const unsigned char* __restrict__ maskB,
    float* __restrict__ out)
{
    const int b = blockIdx.x;
    const int t = threadIdx.x;

    __shared__ float4 Et[4096];      // 64 KB: mean scratch / E tile / Ebar reduce
    __shared__ float4 qk4[256];      // qkp, float4-slot swizzle s^(s>>2)
    __shared__ float4 pt4[256];      // z[] staging for phase E softmax
    __shared__ float4 EbarF4[256];
    __shared__ float4 mu4[32], e14[32], e24[32], gp4[32];
    __shared__ float q[128], heads[128], gl[128];
    __shared__ float qred[8][128];
    __shared__ float ct[128 * 9];    // compat [row][h] pad 9
    __shared__ float mh[8], lh[8], al[8];
    __shared__ float red[16];
    __shared__ float stat[2];
    __shared__ int flagS;

    float* const mu = (float*)mu4;
    float* const e1 = (float*)e14;
    float* const e2 = (float*)e24;
    float* const gp = (float*)gp4;
    float* const pt = (float*)pt4;
    float* const EbarF = (float*)EbarF4;
    float* const qkf = (float*)qk4;

    const float4* E4 = (const float4*)(E + (size_t)b * 128000);

    if (t == 0) flagS = 0;
    // mask-format probe: int32 upload => every word 0/1 => upper 3 bytes zero.
    const uint4 dv = ((const uint4*)maskI)[t];           // first 16 KB
    const unsigned det = (dv.x | dv.y | dv.z | dv.w) & 0xFFFFFF00u;

    const int rr = t >> 3, qq = t & 7;    // phase C/E: 128 rows x 8 octants
    const int c4 = t & 31, sl = t >> 5;   // Ebar: 32 slices x 4 rows

    // Early-issue the phase-C tile-0 prefetch (rows 0..127 — also warms L2
    // for phase A). Held in regs across phases A/B.
    float4 vcur[4];
    #pragma unroll
    for (int i = 0; i < 4; ++i) vcur[i] = E4[rr * 32 + qq * 4 + i];

    // ---- Phase A: graph mean (scratch := Et), first/last embeddings ----
    {
        const int cm = t & 31, sm = t >> 5;
        float4 acc = make_float4(0.f, 0.f, 0.f, 0.f);
        for (int r = sm; r < 1000; r += 32) {
            const float4 v = E4[r * 32 + cm];
            acc.x += v.x; acc.y += v.y; acc.z += v.z; acc.w += v.w;
        }
        Et[t] = acc;
    }
    if (t >= 512 && t < 544) {
        e14[t - 512] = E4[fi[b] * 32 + (t - 512)];
    } else if (t >= 544 && t < 576) {
        e24[t - 544] = E4[li[b] * 32 + (t - 544)];
    }
    __syncthreads();
    if (det) atomicOr(&flagS, 1);
    if (t < 32) {
        float4 acc = Et[t];
        #pragma unroll
        for (int s = 1; s < 32; ++s) {
            const float4 v = Et[s * 32 + t];
            acc.x += v.x; acc.y += v.y; acc.z += v.z; acc.w += v.w;
        }
        const float inv = 1.0f / 1000.0f;
        mu4[t] = make_float4(acc.x * inv, acc.y * inv, acc.z * inv, acc.w * inv);
    }
    __syncthreads();

    // ---- Phase B: q = mu@Wf + e1@Ws[0:128] + e2@Ws[128:256], 8-way k-split ----
    {
        const int part = t >> 7, d = t & 127;
        float acc = 0.f;
        const int k0 = part * 48;
        for (int k = k0; k < k0 + 48; ++k) {
            const float s = (k < 128) ? mu[k] : (k < 256 ? e1[k - 128] : e2[k - 256]);
            const float w = (k < 128) ? Wf[k * 128 + d] : Ws[(k - 128) * 128 + d];
            acc += s * w;
        }
        qred[part][d] = acc;
    }
    __syncthreads();
    if (t < 128) {
        float acc = 0.f;
        #pragma unroll
        for (int p = 0; p < 8; ++p) acc += qred[p][t];
        q[t] = acc;
    }
    __syncthreads();
    // qkp[h][c] -> qk4 (LDS only), slot-swizzled s^(s>>2)
    {
        const int j = t & 127, cg = t >> 7;
        const float qj = q[j];
        for (int c0 = 0; c0 < 128; c0 += 8) {
            const int c = c0 + cg;
            float v = Wn[c * 384 + j] * qj;
            v += __shfl_down(v, 8, 16);
            v += __shfl_down(v, 4, 16);
            v += __shfl_down(v, 2, 16);
            v += __shfl_down(v, 1, 16);
            if ((j & 15) == 0) {
                const int h = j >> 4, s = c >> 2;
                qkf[h * 128 + (s ^ (s >> 2)) * 4 + (c & 3)] = v * 0.25f;
            }
        }
    }
    if (t < 8) { mh[t] = -3e38f; lh[t] = 0.f; }
    __syncthreads();

    const bool useB = (flagS != 0);

    // ---- Phase C: online-softmax glimpse attention, 8 tiles x 128 rows ----
    float4 eacc[8];
    #pragma unroll
    for (int h = 0; h < 8; ++h) eacc[h] = make_float4(0.f, 0.f, 0.f, 0.f);

    for (int tile = 0; tile < 8; ++tile) {
        // prefetch next tile (in flight across all three barriers)
        float4 vnext[4];
        if (tile < 7) {
            const int gn = (tile + 1) * 128 + rr;
            if (gn < 1000) {
                #pragma unroll
                for (int i = 0; i < 4; ++i) vnext[i] = E4[gn * 32 + qq * 4 + i];
            } else {
                #pragma unroll
                for (int i = 0; i < 4; ++i) vnext[i] = make_float4(0.f, 0.f, 0.f, 0.f);
            }
        }
        // stage + compat partials + 8-lane butterfly
        {
            const int g = tile * 128 + rr;
            float pch[8];
            #pragma unroll
            for (int h = 0; h < 8; ++h) pch[h] = 0.f;
            #pragma unroll
            for (int i = 0; i < 4; ++i) {
                const int grp = qq * 4 + i;
                Et[rr * 32 + (grp ^ (rr & 7))] = vcur[i];
                const int sg = grp ^ (grp >> 2);
                #pragma unroll
                for (int h = 0; h < 8; ++h) {
                    const float4 w = qk4[h * 32 + sg];
                    pch[h] += vcur[i].x * w.x + vcur[i].y * w.y + vcur[i].z * w.z + vcur[i].w * w.w;
                }
            }
            #pragma unroll
            for (int m = 1; m <= 4; m <<= 1) {
                #pragma unroll
                for (int h = 0; h < 8; ++h) pch[h] += __shfl_xor(pch[h], m, 64);
            }
            bool msk = (g >= 1000);
            if (!msk) msk = useB ? (maskB[b * 1000 + g] != 0)
                                 : (maskI[b * 1000 + g] != 0);
            ct[rr * 9 + qq] = msk ? NEG : pch[qq];
        }
        __syncthreads();
        // wave0: per-head running max via 8-lane shfl groups
        if (t < 64) {
            const int h = t >> 3, j = t & 7;
            float mt = -3e38f;
            for (int r = j; r < 128; r += 8) mt = fmaxf(mt, ct[r * 9 + h]);
            mt = fmaxf(mt, __shfl_xor(mt, 1, 64));
            mt = fmaxf(mt, __shfl_xor(mt, 2, 64));
            mt = fmaxf(mt, __shfl_xor(mt, 4, 64));
            if (j == 0) {
                const float mnew = fmaxf(mh[h], mt);
                al[h] = __expf(mh[h] - mnew);
                mh[h] = mnew;
            }
        }
        __syncthreads();
        // Ebar accumulate with inline exp (4 rows/thread); wave0 also does l
        {
            float alr[8], mhr[8];
            #pragma unroll
            for (int h = 0; h < 8; ++h) { alr[h] = al[h]; mhr[h] = mh[h]; }
            #pragma unroll
            for (int h = 0; h < 8; ++h) {
                eacc[h].x *= alr[h]; eacc[h].y *= alr[h];
                eacc[h].z *= alr[h]; eacc[h].w *= alr[h];
            }
            #pragma unroll
            for (int j2 = 0; j2 < 4; ++j2) {
                const int r = sl * 4 + j2;
                const float4 ev = Et[r * 32 + (c4 ^ (r & 7))];
                float p[8];
                #pragma unroll
                for (int h = 0; h < 8; ++h) p[h] = __expf(ct[r * 9 + h] - mhr[h]);
                #pragma unroll
                for (int h = 0; h < 8; ++h) {
                    eacc[h].x += p[h] * ev.x; eacc[h].y += p[h] * ev.y;
                    eacc[h].z += p[h] * ev.z; eacc[h].w += p[h] * ev.w;
                }
            }
        }
        if (t < 64) {
            const int h = t >> 3, j = t & 7;
            const float mhh = mh[h];
            float s = 0.f;
            for (int r = j; r < 128; r += 8) s += __expf(ct[r * 9 + h] - mhh);
            s += __shfl_xor(s, 1, 64);
            s += __shfl_xor(s, 2, 64);
            s += __shfl_xor(s, 4, 64);
            if (j == 0) lh[h] = lh[h] * al[h] + s;
        }
        if (tile < 7) {
            #pragma unroll
            for (int i = 0; i < 4; ++i) vcur[i] = vnext[i];
        }
        __syncthreads();
    }

    // ---- reduce 32 slice-partials in two stages (Et holds 16 slices) ----
    if (sl >= 16) {
        #pragma unroll
        for (int h = 0; h < 8; ++h) Et[(sl - 16) * 256 + h * 32 + c4] = eacc[h];
    }
    __syncthreads();
    if (sl < 16) {
        #pragma unroll
        for (int h = 0; h < 8; ++h) {
            const float4 o = Et[sl * 256 + h * 32 + c4];
            eacc[h].x += o.x; eacc[h].y += o.y; eacc[h].z += o.z; eacc[h].w += o.w;
            Et[sl * 256 + h * 32 + c4] = eacc[h];
        }
    }
    __syncthreads();
    if (t < 256) {
        const int h = t >> 5, cc = t & 31;
        float4 s = make_float4(0.f, 0.f, 0.f, 0.f);
        #pragma unroll
        for (int s2 = 0; s2 < 16; ++s2) {
            const float4 v = Et[s2 * 256 + h * 32 + cc];
            s.x += v.x; s.y += v.y; s.z += v.z; s.w += v.w;
        }
        const float invl = 1.0f / lh[h];
        EbarF4[h * 32 + cc] = make_float4(s.x * invl, s.y * invl, s.z * invl, s.w * invl);
    }
    __syncthreads();

    // ---- Phase D: heads -> glimpse -> gp, 8-way k-split each ----
    {
        const int part = t >> 7, d = t & 127, h = d >> 4;
        float acc = 0.f;
        const int c0 = part * 16;
        for (int c = c0; c < c0 + 16; ++c) acc += EbarF[h * 128 + c] * Wn[c * 384 + 128 + d];
        qred[part][d] = acc;
    }
    __syncthreads();
    if (t < 128) {
        float acc = 0.f;
        #pragma unroll
        for (int p = 0; p < 8; ++p) acc += qred[p][t];
        heads[t] = acc;
    }
    __syncthreads();
    {
        const int part = t >> 7, d = t & 127;
        float acc = 0.f;
        const int j0 = part * 16;
        for (int j = j0; j < j0 + 16; ++j) acc += heads[j] * Wo[j * 128 + d];
        qred[part][d] = acc;
    }
    __syncthreads();
    if (t < 128) {
        float acc = 0.f;
        #pragma unroll
        for (int p = 0; p < 8; ++p) acc += qred[p][t];
        gl[t] = acc;
    }
    __syncthreads();
    {
        const int part = t >> 7, c = t & 127;
        float acc = 0.f;
        const int d0 = part * 16;
        for (int d = d0; d < d0 + 16; ++d) acc += Wn[c * 384 + 256 + d] * gl[d];
        qred[part][c] = acc;
    }
    __syncthreads();
    if (t < 128) {
        float acc = 0.f;
        #pragma unroll
        for (int p = 0; p < 8; ++p) acc += qred[p][t];
        gp[t] = acc * 0.08838834764831845f;   // 1/sqrt(128)
    }
    __syncthreads();

    // ---- Phase E: logits via shfl butterfly — no barriers in tile loop ----
    for (int tile = 0; tile < 8; ++tile) {
        const int g = tile * 128 + rr;
        float acc = 0.f;
        if (g < 1000) {
            #pragma unroll
            for (int i = 0; i < 4; ++i) {
                const float4 v = E4[g * 32 + qq * 4 + i];
                const float4 w = gp4[qq * 4 + i];
                acc += v.x * w.x + v.y * w.y + v.z * w.z + v.w * w.w;
            }
        }
        acc += __shfl_xor(acc, 1, 64);
        acc += __shfl_xor(acc, 2, 64);
        acc += __shfl_xor(acc, 4, 64);
        if (qq == 0 && g < 1000) {
            float zz = 10.0f * tanhf(acc);
            const bool m = useB ? (maskB[b * 1000 + g] != 0)
                                : (maskI[b * 1000 + g] != 0);
            if (m) zz = NEG;
            pt[g] = zz;
        }
    }
    __syncthreads();
    float v = (t < 1000) ? pt[t] : -3e38f;
    #pragma unroll
    for (int off = 32; off > 0; off >>= 1) v = fmaxf(v, __shfl_down(v, off, 64));
    if ((t & 63) == 0) red[t >> 6] = v;
    __syncthreads();
    if (t == 0) {
        float m = red[0];
        for (int i = 1; i < 16; ++i) m = fmaxf(m, red[i]);
        stat[0] = m;
    }
    __syncthreads();
    float sv = (t < 1000) ? __expf(pt[t] - stat[0]) : 0.f;
    #pragma unroll
    for (int off = 32; off > 0; off >>= 1) sv += __shfl_down(sv, off, 64);
    if ((t & 63) == 0) red[t >> 6] = sv;
    __syncthreads();
    if (t == 0) {
        float s = 0.f;
        for (int i = 0; i < 16; ++i) s += red[i];
        stat[1] = stat[0] + __logf(s);
    }
    __syncthreads();
    if (t < 1000)
        out[(size_t)b * 1000 + t] = pt[t] - stat[1];
}

// ---------------------------------------------------------------------------
extern "C" void kernel_launch(void* const* d_in, const int* in_sizes, int n_in,
                              void* d_out, int out_size, void* d_ws, size_t ws_size,
                              hipStream_t stream) {
    const float* E  = (const float*)d_in[0];
    const float* Wn = (const float*)d_in[1];
    const float* Wf = (const float*)d_in[2];
    const float* Ws = (const float*)d_in[3];
    const float* Wo = (const float*)d_in[4];
    const int*   fi = (const int*)d_in[5];
    const int*   li = (const int*)d_in[6];
    const int*   maskI = (const int*)d_in[7];
    const unsigned char* maskB = (const unsigned char*)d_in[7];
    float* out = (float*)d_out;

    k_fused<<<256, 1024, 0, stream>>>(E, Wn, Wf, Ws, Wo, fi, li, maskI, maskB, out);
}

// Round 8
// 304.125 us; speedup vs baseline: 1.3189x; 1.2997x over previous
//
#include <hip/hip_runtime.h>

// Problem: B=256, N=1000, D=128, H=8, dk=16. grid=256 (one block per b) —
// 1 block/CU, occupancy == waves/block (1024 thr = 16 waves).
//
// R8: R5's register profile (NO tile prefetch — R6/R7's vcur/vnext spilled at
// the 64-VGPR cap: WRITE_SIZE 3->418 MB, launch_bounds(,4) did NOT lift the
// cap) + R6's cheap barrier reductions (wave0 shfl m/l, inline exp, phase E
// shfl butterfly). Phase C: 3 barriers/tile. All loads short-lived.
//
// Math:
//   qkp[h,c]  = 0.25 * sum_e W_node[c, h*16+e] * q[h*16+e]
//   compat[h,n] = sum_c E[n,c] * qkp[h,c]            (masked -> -1e9)
//   Ebar[h,c] = sum_n softmax_n(compat)[h,n] * E[n,c] (online softmax)
//   heads -> glimpse -> gp[c] = (1/sqrt(128)) sum_d W_node[c,256+d]*glimpse[d]
//   logits[n] = sum_c E[n,c] * gp[c]; z=10*tanh; mask; log_softmax.

#define NEG (-1e9f)

__global__ __launch_bounds__(1024) void k_fused(
    const float* __restrict__ E, const float* __restrict__ Wn,
    const float* __restrict__ Wf, const float* __restrict__ Ws,
    const float* __restrict__ Wo,
    const int* __restrict__ fi, const int* __restrict__ li,
    const int* __restrict__ maskI, const unsigned char* __restrict__ maskB,
    float* __restrict__ out)
{
    const int b = blockIdx.x;
    const int t = threadIdx.x;

    __shared__ float4 Et[4096];      // 64 KB: mean scratch / E tile / Ebar reduce
    __shared__ float4 qk4[256];      // qkp, float4-slot swizzle s^(s>>2)
    __shared__ float4 pt4[256];      // z[] staging for phase E softmax
    __shared__ float4 EbarF4[256];
    __shared__ float4 mu4[32], e14[32], e24[32], gp4[32];
    __shared__ float q[128], heads[128], gl[128];
    __shared__ float qred[8][128];
    __shared__ float ct[128 * 9];    // compat [row][h] pad 9
    __shared__ float mh[8], lh[8], al[8];
    __shared__ float red[16];
    __shared__ float stat[2];
    __shared__ int flagS;

    float* const mu = (float*)mu4;
    float* const e1 = (float*)e14;
    float* const e2 = (float*)e24;
    float* const gp = (float*)gp4;
    float* const pt = (float*)pt4;
    float* const EbarF = (float*)EbarF4;
    float* const qkf = (float*)qk4;

    const float4* E4 = (const float4*)(E + (size_t)b * 128000);

    if (t == 0) flagS = 0;
    // mask-format probe: int32 upload => every word 0/1 => upper 3 bytes zero.
    const uint4 dv = ((const uint4*)maskI)[t];           // first 16 KB
    const unsigned det = (dv.x | dv.y | dv.z | dv.w) & 0xFFFFFF00u;

    const int rr = t >> 3, qq = t & 7;    // phase C/E: 128 rows x 8 octants
    const int c4 = t & 31, sl = t >> 5;   // Ebar: 32 slices x 4 rows

    // ---- Phase A: graph mean (scratch := Et), first/last embeddings ----
    {
        const int cm = t & 31, sm = t >> 5;
        float4 acc = make_float4(0.f, 0.f, 0.f, 0.f);
        for (int r = sm; r < 1000; r += 32) {
            const float4 v = E4[r * 32 + cm];
            acc.x += v.x; acc.y += v.y; acc.z += v.z; acc.w += v.w;
        }
        Et[t] = acc;
    }
    if (t >= 512 && t < 544) {
        e14[t - 512] = E4[fi[b] * 32 + (t - 512)];
    } else if (t >= 544 && t < 576) {
        e24[t - 544] = E4[li[b] * 32 + (t - 544)];
    }
    __syncthreads();
    if (det) atomicOr(&flagS, 1);
    if (t < 32) {
        float4 acc = Et[t];
        #pragma unroll
        for (int s = 1; s < 32; ++s) {
            const float4 v = Et[s * 32 + t];
            acc.x += v.x; acc.y += v.y; acc.z += v.z; acc.w += v.w;
        }
        const float inv = 1.0f / 1000.0f;
        mu4[t] = make_float4(acc.x * inv, acc.y * inv, acc.z * inv, acc.w * inv);
    }
    __syncthreads();

    // ---- Phase B: q = mu@Wf + e1@Ws[0:128] + e2@Ws[128:256], 8-way k-split ----
    {
        const int part = t >> 7, d = t & 127;
        float acc = 0.f;
        const int k0 = part * 48;
        for (int k = k0; k < k0 + 48; ++k) {
            const float s = (k < 128) ? mu[k] : (k < 256 ? e1[k - 128] : e2[k - 256]);
            const float w = (k < 128) ? Wf[k * 128 + d] : Ws[(k - 128) * 128 + d];
            acc += s * w;
        }
        qred[part][d] = acc;
    }
    __syncthreads();
    if (t < 128) {
        float acc = 0.f;
        #pragma unroll
        for (int p = 0; p < 8; ++p) acc += qred[p][t];
        q[t] = acc;
    }
    __syncthreads();
    // qkp[h][c] -> qk4 (LDS only), slot-swizzled s^(s>>2)
    {
        const int j = t & 127, cg = t >> 7;
        const float qj = q[j];
        for (int c0 = 0; c0 < 128; c0 += 8) {
            const int c = c0 + cg;
            float v = Wn[c * 384 + j] * qj;
            v += __shfl_down(v, 8, 16);
            v += __shfl_down(v, 4, 16);
            v += __shfl_down(v, 2, 16);
            v += __shfl_down(v, 1, 16);
            if ((j & 15) == 0) {
                const int h = j >> 4, s = c >> 2;
                qkf[h * 128 + (s ^ (s >> 2)) * 4 + (c & 3)] = v * 0.25f;
            }
        }
    }
    if (t < 8) { mh[t] = -3e38f; lh[t] = 0.f; }
    __syncthreads();

    const bool useB = (flagS != 0);

    // ---- Phase C: online-softmax glimpse attention, 8 tiles x 128 rows ----
    // Per tile: [stage+compat] B1 [wave0: m,al] B2 [Ebar inline-exp + wave0: l] B3
    float4 eacc[8];
    #pragma unroll
    for (int h = 0; h < 8; ++h) eacc[h] = make_float4(0.f, 0.f, 0.f, 0.f);

    for (int tile = 0; tile < 8; ++tile) {
        // stage + compat partials + 8-lane butterfly (loads short-lived)
        {
            const int g = tile * 128 + rr;
            float4 v[4];
            if (g < 1000) {
                #pragma unroll
                for (int i = 0; i < 4; ++i) v[i] = E4[g * 32 + qq * 4 + i];
            } else {
                #pragma unroll
                for (int i = 0; i < 4; ++i) v[i] = make_float4(0.f, 0.f, 0.f, 0.f);
            }
            float pch[8];
            #pragma unroll
            for (int h = 0; h < 8; ++h) pch[h] = 0.f;
            #pragma unroll
            for (int i = 0; i < 4; ++i) {
                const int grp = qq * 4 + i;
                Et[rr * 32 + (grp ^ (rr & 7))] = v[i];
                const int sg = grp ^ (grp >> 2);
                #pragma unroll
                for (int h = 0; h < 8; ++h) {
                    const float4 w = qk4[h * 32 + sg];
                    pch[h] += v[i].x * w.x + v[i].y * w.y + v[i].z * w.z + v[i].w * w.w;
                }
            }
            #pragma unroll
            for (int m = 1; m <= 4; m <<= 1) {
                #pragma unroll
                for (int h = 0; h < 8; ++h) pch[h] += __shfl_xor(pch[h], m, 64);
            }
            bool msk = (g >= 1000);
            if (!msk) msk = useB ? (maskB[b * 1000 + g] != 0)
                                 : (maskI[b * 1000 + g] != 0);
            ct[rr * 9 + qq] = msk ? NEG : pch[qq];
        }
        __syncthreads();
        // wave0: per-head running max via 8-lane shfl groups
        if (t < 64) {
            const int h = t >> 3, j = t & 7;
            float mt = -3e38f;
            for (int r = j; r < 128; r += 8) mt = fmaxf(mt, ct[r * 9 + h]);
            mt = fmaxf(mt, __shfl_xor(mt, 1, 64));
            mt = fmaxf(mt, __shfl_xor(mt, 2, 64));
            mt = fmaxf(mt, __shfl_xor(mt, 4, 64));
            if (j == 0) {
                const float mnew = fmaxf(mh[h], mt);
                al[h] = __expf(mh[h] - mnew);
                mh[h] = mnew;
            }
        }
        __syncthreads();
        // Ebar accumulate with inline exp (4 rows/thread); wave0 also does l
        {
            float alr[8], mhr[8];
            #pragma unroll
            for (int h = 0; h < 8; ++h) { alr[h] = al[h]; mhr[h] = mh[h]; }
            #pragma unroll
            for (int h = 0; h < 8; ++h) {
                eacc[h].x *= alr[h]; eacc[h].y *= alr[h];
                eacc[h].z *= alr[h]; eacc[h].w *= alr[h];
            }
            #pragma unroll
            for (int j2 = 0; j2 < 4; ++j2) {
                const int r = sl * 4 + j2;
                const float4 ev = Et[r * 32 + (c4 ^ (r & 7))];
                float p[8];
                #pragma unroll
                for (int h = 0; h < 8; ++h) p[h] = __expf(ct[r * 9 + h] - mhr[h]);
                #pragma unroll
                for (int h = 0; h < 8; ++h) {
                    eacc[h].x += p[h] * ev.x; eacc[h].y += p[h] * ev.y;
                    eacc[h].z += p[h] * ev.z; eacc[h].w += p[h] * ev.w;
                }
            }
        }
        if (t < 64) {
            const int h = t >> 3, j = t & 7;
            const float mhh = mh[h];
            float s = 0.f;
            for (int r = j; r < 128; r += 8) s += __expf(ct[r * 9 + h] - mhh);
            s += __shfl_xor(s, 1, 64);
            s += __shfl_xor(s, 2, 64);
            s += __shfl_xor(s, 4, 64);
            if (j == 0) lh[h] = lh[h] * al[h] + s;
        }
        __syncthreads();
    }

    // ---- reduce 32 slice-partials in two stages (Et holds 16 slices) ----
    if (sl >= 16) {
        #pragma unroll
        for (int h = 0; h < 8; ++h) Et[(sl - 16) * 256 + h * 32 + c4] = eacc[h];
    }
    __syncthreads();
    if (sl < 16) {
        #pragma unroll
        for (int h = 0; h < 8; ++h) {
            const float4 o = Et[sl * 256 + h * 32 + c4];
            eacc[h].x += o.x; eacc[h].y += o.y; eacc[h].z += o.z; eacc[h].w += o.w;
            Et[sl * 256 + h * 32 + c4] = eacc[h];
        }
    }
    __syncthreads();
    if (t < 256) {
        const int h = t >> 5, cc = t & 31;
        float4 s = make_float4(0.f, 0.f, 0.f, 0.f);
        #pragma unroll
        for (int s2 = 0; s2 < 16; ++s2) {
            const float4 v = Et[s2 * 256 + h * 32 + cc];
            s.x += v.x; s.y += v.y; s.z += v.z; s.w += v.w;
        }
        const float invl = 1.0f / lh[h];
        EbarF4[h * 32 + cc] = make_float4(s.x * invl, s.y * invl, s.z * invl, s.w * invl);
    }
    __syncthreads();

    // ---- Phase D: heads -> glimpse -> gp, 8-way k-split each ----
    {
        const int part = t >> 7, d = t & 127, h = d >> 4;
        float acc = 0.f;
        const int c0 = part * 16;
        for (int c = c0; c < c0 + 16; ++c) acc += EbarF[h * 128 + c] * Wn[c * 384 + 128 + d];
        qred[part][d] = acc;
    }
    __syncthreads();
    if (t < 128) {
        float acc = 0.f;
        #pragma unroll
        for (int p = 0; p < 8; ++p) acc += qred[p][t];
        heads[t] = acc;
    }
    __syncthreads();
    {
        const int part = t >> 7, d = t & 127;
        float acc = 0.f;
        const int j0 = part * 16;
        for (int j = j0; j < j0 + 16; ++j) acc += heads[j] * Wo[j * 128 + d];
        qred[part][d] = acc;
    }
    __syncthreads();
    if (t < 128) {
        float acc = 0.f;
        #pragma unroll
        for (int p = 0; p < 8; ++p) acc += qred[p][t];
        gl[t] = acc;
    }
    __syncthreads();
    {
        const int part = t >> 7, c = t & 127;
        float acc = 0.f;
        const int d0 = part * 16;
        for (int d = d0; d < d0 + 16; ++d) acc += Wn[c * 384 + 256 + d] * gl[d];
        qred[part][c] = acc;
    }
    __syncthreads();
    if (t < 128) {
        float acc = 0.f;
        #pragma unroll
        for (int p = 0; p < 8; ++p) acc += qred[p][t];
        gp[t] = acc * 0.08838834764831845f;   // 1/sqrt(128)
    }
    __syncthreads();

    // ---- Phase E: logits via shfl butterfly — no barriers in tile loop ----
    for (int tile = 0; tile < 8; ++tile) {
        const int g = tile * 128 + rr;
        float acc = 0.f;
        if (g < 1000) {
            #pragma unroll
            for (int i = 0; i < 4; ++i) {
                const float4 v = E4[g * 32 + qq * 4 + i];
                const float4 w = gp4[qq * 4 + i];
                acc += v.x * w.x + v.y * w.y + v.z * w.z + v.w * w.w;
            }
        }
        acc += __shfl_xor(acc, 1, 64);
        acc += __shfl_xor(acc, 2, 64);
        acc += __shfl_xor(acc, 4, 64);
        if (qq == 0 && g < 1000) {
            float zz = 10.0f * tanhf(acc);
            const bool m = useB ? (maskB[b * 1000 + g] != 0)
                                : (maskI[b * 1000 + g] != 0);
            if (m) zz = NEG;
            pt[g] = zz;
        }
    }
    __syncthreads();
    float v = (t < 1000) ? pt[t] : -3e38f;
    #pragma unroll
    for (int off = 32; off > 0; off >>= 1) v = fmaxf(v, __shfl_down(v, off, 64));
    if ((t & 63) == 0) red[t >> 6] = v;
    __syncthreads();
    if (t == 0) {
        float m = red[0];
        for (int i = 1; i < 16; ++i) m = fmaxf(m, red[i]);
        stat[0] = m;
    }
    __syncthreads();
    float sv = (t < 1000) ? __expf(pt[t] - stat[0]) : 0.f;
    #pragma unroll
    for (int off = 32; off > 0; off >>= 1) sv += __shfl_down(sv, off, 64);
    if ((t & 63) == 0) red[t >> 6] = sv;
    __syncthreads();
    if (t == 0) {
        float s = 0.f;
        for (int i = 0; i < 16; ++i) s += red[i];
        stat[1] = stat[0] + __logf(s);
    }
    __syncthreads();
    if (t < 1000)
        out[(size_t)b * 1000 + t] = pt[t] - stat[1];
}

// ---------------------------------------------------------------------------
extern "C" void kernel_launch(void* const* d_in, const int* in_sizes, int n_in,
                              void* d_out, int out_size, void* d_ws, size_t ws_size,
                              hipStream_t stream) {
    const float* E  = (const float*)d_in[0];
    const float* Wn = (const float*)d_in[1];
    const float* Wf = (const float*)d_in[2];
    const float* Ws = (const float*)d_in[3];
    const float* Wo = (const float*)d_in[4];
    const int*   fi = (const int*)d_in[5];
    const int*   li = (const int*)d_in[6];
    const int*   maskI = (const int*)d_in[7];
    const unsigned char* maskB = (const unsigned char*)d_in[7];
    float* out = (float*)d_out;

    k_fused<<<256, 1024, 0, stream>>>(E, Wn, Wf, Ws, Wo, fi, li, maskI, maskB, out);
}

// Round 9
// 288.354 us; speedup vs baseline: 1.3910x; 1.0547x over previous
//
#include <hip/hip_runtime.h>

// Problem: B=256, N=1000, D=128, H=8, dk=16. grid=256 (one block per b).
//
// R9: flash-decoding-style PER-WAVE online softmax. Phase C is wave-local
// (wave w stages+consumes rows 8w..8w+7 of every tile), so each wave keeps
// its own (m_w, l_w, eacc) in registers/SGPRs and the tile loop has ZERO
// __syncthreads. One merge at the end rescales by exp(m_w - m_glob)
// (all-masked waves self-zero: expf(-1e9 - x) == 0 in fp32).
// R5..R8 established: lockstep barrier structure plateaus at 140-160 us;
// VGPR cap is 64 (launch_bounds(,4) does NOT lift it) so wave-uniform
// m/l go to SGPRs via readfirstlane.
//
// Math:
//   qkp[h,c]  = 0.25 * sum_e W_node[c, h*16+e] * q[h*16+e]
//   compat[h,n] = sum_c E[n,c] * qkp[h,c]            (masked -> -1e9)
//   Ebar[h,c] = sum_n softmax_n(compat)[h,n] * E[n,c] (split online softmax)
//   heads -> glimpse -> gp[c] = (1/sqrt(128)) sum_d W_node[c,256+d]*glimpse[d]
//   logits[n] = sum_c E[n,c] * gp[c]; z=10*tanh; mask; log_softmax.

#define NEG (-1e9f)

__device__ __forceinline__ float rfl(float x) {
    return __int_as_float(__builtin_amdgcn_readfirstlane(__float_as_int(x)));
}

__global__ __launch_bounds__(1024) void k_fused(
    const float* __restrict__ E, const float* __restrict__ Wn,
    const float* __restrict__ Wf, const float* __restrict__ Ws,
    const float* __restrict__ Wo,
    const int* __restrict__ fi, const int* __restrict__ li,
    const int* __restrict__ maskI, const unsigned char* __restrict__ maskB,
    float* __restrict__ out)
{
    const int b = blockIdx.x;
    const int t = threadIdx.x;

    __shared__ float4 Et[4096];      // 64 KB: mean scratch / E tile / Ebar reduce
    __shared__ float4 qk4[256];      // qkp, float4-slot swizzle s^(s>>2)
    __shared__ float4 pt4[256];      // per-tile p (wave-local); z[] in phase E
    __shared__ float4 EbarF4[256];
    __shared__ float4 mu4[32], e14[32], e24[32], gp4[32];
    __shared__ float q[128], heads[128], gl[128];
    __shared__ float qred[8][128];   // k-split partials; wave-merge scratch
    __shared__ float mh[8], lh[8];
    __shared__ float red[16];
    __shared__ float stat[2];
    __shared__ int flagS;

    float* const mu = (float*)mu4;
    float* const e1 = (float*)e14;
    float* const e2 = (float*)e24;
    float* const gp = (float*)gp4;
    float* const pt = (float*)pt4;
    float* const EbarF = (float*)EbarF4;
    float* const qkf = (float*)qk4;
    float* const qrf = (float*)qred;

    const float4* E4 = (const float4*)(E + (size_t)b * 128000);

    if (t == 0) flagS = 0;
    // mask-format probe: int32 upload => every word 0/1 => upper 3 bytes zero.
    const uint4 dv = ((const uint4*)maskI)[t];           // first 16 KB
    const unsigned det = (dv.x | dv.y | dv.z | dv.w) & 0xFFFFFF00u;

    const int rr = t >> 3, qq = t & 7;    // phase C/E: 128 rows x 8 octants
    const int c4 = t & 31, sl = t >> 5;   // Ebar: 32 slices x 4 rows
    const int wv = t >> 6;                // wave index

    // ---- Phase A: graph mean (scratch := Et), first/last embeddings ----
    {
        const int cm = t & 31, sm = t >> 5;
        float4 acc = make_float4(0.f, 0.f, 0.f, 0.f);
        for (int r = sm; r < 1000; r += 32) {
            const float4 v = E4[r * 32 + cm];
            acc.x += v.x; acc.y += v.y; acc.z += v.z; acc.w += v.w;
        }
        Et[t] = acc;
    }
    if (t >= 512 && t < 544) {
        e14[t - 512] = E4[fi[b] * 32 + (t - 512)];
    } else if (t >= 544 && t < 576) {
        e24[t - 544] = E4[li[b] * 32 + (t - 544)];
    }
    __syncthreads();
    if (det) atomicOr(&flagS, 1);
    if (t < 32) {
        float4 acc = Et[t];
        #pragma unroll
        for (int s = 1; s < 32; ++s) {
            const float4 v = Et[s * 32 + t];
            acc.x += v.x; acc.y += v.y; acc.z += v.z; acc.w += v.w;
        }
        const float inv = 1.0f / 1000.0f;
        mu4[t] = make_float4(acc.x * inv, acc.y * inv, acc.z * inv, acc.w * inv);
    }
    __syncthreads();

    // ---- Phase B: q = mu@Wf + e1@Ws[0:128] + e2@Ws[128:256], 8-way k-split ----
    {
        const int part = t >> 7, d = t & 127;
        float acc = 0.f;
        const int k0 = part * 48;
        for (int k = k0; k < k0 + 48; ++k) {
            const float s = (k < 128) ? mu[k] : (k < 256 ? e1[k - 128] : e2[k - 256]);
            const float w = (k < 128) ? Wf[k * 128 + d] : Ws[(k - 128) * 128 + d];
            acc += s * w;
        }
        qred[part][d] = acc;
    }
    __syncthreads();
    if (t < 128) {
        float acc = 0.f;
        #pragma unroll
        for (int p = 0; p < 8; ++p) acc += qred[p][t];
        q[t] = acc;
    }
    __syncthreads();
    // qkp[h][c] -> qk4 (LDS only), slot-swizzled s^(s>>2)
    {
        const int j = t & 127, cg = t >> 7;
        const float qj = q[j];
        for (int c0 = 0; c0 < 128; c0 += 8) {
            const int c = c0 + cg;
            float v = Wn[c * 384 + j] * qj;
            v += __shfl_down(v, 8, 16);
            v += __shfl_down(v, 4, 16);
            v += __shfl_down(v, 2, 16);
            v += __shfl_down(v, 1, 16);
            if ((j & 15) == 0) {
                const int h = j >> 4, s = c >> 2;
                qkf[h * 128 + (s ^ (s >> 2)) * 4 + (c & 3)] = v * 0.25f;
            }
        }
    }
    __syncthreads();

    const bool useB = (flagS != 0);

    // ---- Phase C: wave-local online-softmax attention, 8 tiles x 128 rows,
    //      ZERO block barriers in the loop ----
    float s_m[8], s_l[8];
    #pragma unroll
    for (int h = 0; h < 8; ++h) { s_m[h] = -3e38f; s_l[h] = 0.f; }
    float4 eacc[8];
    #pragma unroll
    for (int h = 0; h < 8; ++h) eacc[h] = make_float4(0.f, 0.f, 0.f, 0.f);

    for (int tile = 0; tile < 8; ++tile) {
        const int g = tile * 128 + rr;
        float pch[8];
        #pragma unroll
        for (int h = 0; h < 8; ++h) pch[h] = 0.f;
        {   // load + stage (wave-local rows) + compat partials
            float4 v[4];
            if (g < 1000) {
                #pragma unroll
                for (int i = 0; i < 4; ++i) v[i] = E4[g * 32 + qq * 4 + i];
            } else {
                #pragma unroll
                for (int i = 0; i < 4; ++i) v[i] = make_float4(0.f, 0.f, 0.f, 0.f);
            }
            #pragma unroll
            for (int i = 0; i < 4; ++i) {
                const int grp = qq * 4 + i;
                Et[rr * 32 + (grp ^ (rr & 7))] = v[i];
                const int sg = grp ^ (grp >> 2);
                #pragma unroll
                for (int h = 0; h < 8; ++h) {
                    const float4 w = qk4[h * 32 + sg];
                    pch[h] += v[i].x * w.x + v[i].y * w.y + v[i].z * w.z + v[i].w * w.w;
                }
            }
        }
        // octant butterfly -> every lane has full compat[row][h] for all h
        #pragma unroll
        for (int m = 1; m <= 4; m <<= 1) {
            #pragma unroll
            for (int h = 0; h < 8; ++h) pch[h] += __shfl_xor(pch[h], m, 64);
        }
        bool msk = (g >= 1000);
        if (!msk) msk = useB ? (maskB[b * 1000 + g] != 0)
                             : (maskI[b * 1000 + g] != 0);
        if (msk) {
            #pragma unroll
            for (int h = 0; h < 8; ++h) pch[h] = NEG;
        }
        // wave tile-max over its 8 rows (bits 3..5), then m/al update (SGPR)
        float al[8];
        #pragma unroll
        for (int h = 0; h < 8; ++h) {
            float x = pch[h];
            x = fmaxf(x, __shfl_xor(x, 8, 64));
            x = fmaxf(x, __shfl_xor(x, 16, 64));
            x = fmaxf(x, __shfl_xor(x, 32, 64));
            const float mn = rfl(fmaxf(s_m[h], x));
            al[h] = __expf(s_m[h] - mn);
            s_m[h] = mn;
        }
        // e per lane (its row); l update via row butterfly
        float e[8];
        #pragma unroll
        for (int h = 0; h < 8; ++h) {
            e[h] = __expf(pch[h] - s_m[h]);
            float x = e[h];
            x += __shfl_xor(x, 8, 64);
            x += __shfl_xor(x, 16, 64);
            x += __shfl_xor(x, 32, 64);
            s_l[h] = rfl(s_l[h] * al[h] + x);
        }
        if (qq == 0)      pt4[rr * 2]     = make_float4(e[0], e[1], e[2], e[3]);
        else if (qq == 1) pt4[rr * 2 + 1] = make_float4(e[4], e[5], e[6], e[7]);
        // wave-local LDS RAW: drain DS queue, block reordering (no s_barrier)
        asm volatile("s_waitcnt lgkmcnt(0)" ::: "memory");
        // Ebar accumulate: rows (t>>5)*4+j are within this wave's 8 rows
        #pragma unroll
        for (int h = 0; h < 8; ++h) {
            eacc[h].x *= al[h]; eacc[h].y *= al[h];
            eacc[h].z *= al[h]; eacc[h].w *= al[h];
        }
        #pragma unroll
        for (int j = 0; j < 4; ++j) {
            const int r = sl * 4 + j;
            const float4 ev = Et[r * 32 + (c4 ^ (r & 7))];
            const float4 p0 = pt4[r * 2];
            const float4 p1 = pt4[r * 2 + 1];
            eacc[0].x += p0.x * ev.x; eacc[0].y += p0.x * ev.y; eacc[0].z += p0.x * ev.z; eacc[0].w += p0.x * ev.w;
            eacc[1].x += p0.y * ev.x; eacc[1].y += p0.y * ev.y; eacc[1].z += p0.y * ev.z; eacc[1].w += p0.y * ev.w;
            eacc[2].x += p0.z * ev.x; eacc[2].y += p0.z * ev.y; eacc[2].z += p0.z * ev.z; eacc[2].w += p0.z * ev.w;
            eacc[3].x += p0.w * ev.x; eacc[3].y += p0.w * ev.y; eacc[3].z += p0.w * ev.z; eacc[3].w += p0.w * ev.w;
            eacc[4].x += p1.x * ev.x; eacc[4].y += p1.x * ev.y; eacc[4].z += p1.x * ev.z; eacc[4].w += p1.x * ev.w;
            eacc[5].x += p1.y * ev.x; eacc[5].y += p1.y * ev.y; eacc[5].z += p1.y * ev.z; eacc[5].w += p1.y * ev.w;
            eacc[6].x += p1.z * ev.x; eacc[6].y += p1.z * ev.y; eacc[6].z += p1.z * ev.z; eacc[6].w += p1.z * ev.w;
            eacc[7].x += p1.w * ev.x; eacc[7].y += p1.w * ev.y; eacc[7].z += p1.w * ev.z; eacc[7].w += p1.w * ev.w;
        }
        // writes next tile's Et only after this wave's reads (in-order wave) —
        // the lgkmcnt(0) at the top of next iteration orders them too.
        asm volatile("" ::: "memory");
    }

    // ---- merge 16 waves' (m,l): global m, factors f_w, global l ----
    if ((t & 63) == 0) {
        #pragma unroll
        for (int h = 0; h < 8; ++h) {
            qrf[wv * 32 + h] = s_m[h];
            qrf[wv * 32 + 8 + h] = s_l[h];
        }
    }
    __syncthreads();
    if (t < 8) {
        float m = qrf[t];
        for (int w2 = 1; w2 < 16; ++w2) m = fmaxf(m, qrf[w2 * 32 + t]);
        mh[t] = m;
    }
    __syncthreads();
    if (t < 128) {
        const int w2 = t >> 3, h = t & 7;
        const float f = __expf(qrf[w2 * 32 + h] - mh[h]);
        qrf[w2 * 32 + 16 + h] = f;
        qrf[w2 * 32 + 24 + h] = qrf[w2 * 32 + 8 + h] * f;
    }
    __syncthreads();
    if (t < 8) {
        float s = 0.f;
        for (int w2 = 0; w2 < 16; ++w2) s += qrf[w2 * 32 + 24 + t];
        lh[t] = s;
    }
    {   // rescale this wave's accumulator into the global frame
        float fw[8];
        #pragma unroll
        for (int h = 0; h < 8; ++h) fw[h] = qrf[wv * 32 + 16 + h];
        #pragma unroll
        for (int h = 0; h < 8; ++h) {
            eacc[h].x *= fw[h]; eacc[h].y *= fw[h];
            eacc[h].z *= fw[h]; eacc[h].w *= fw[h];
        }
    }
    __syncthreads();

    // ---- reduce 32 slice-partials in two stages (Et holds 16 slices) ----
    if (sl >= 16) {
        #pragma unroll
        for (int h = 0; h < 8; ++h) Et[(sl - 16) * 256 + h * 32 + c4] = eacc[h];
    }
    __syncthreads();
    if (sl < 16) {
        #pragma unroll
        for (int h = 0; h < 8; ++h) {
            const float4 o = Et[sl * 256 + h * 32 + c4];
            eacc[h].x += o.x; eacc[h].y += o.y; eacc[h].z += o.z; eacc[h].w += o.w;
            Et[sl * 256 + h * 32 + c4] = eacc[h];
        }
    }
    __syncthreads();
    if (t < 256) {
        const int h = t >> 5, cc = t & 31;
        float4 s = make_float4(0.f, 0.f, 0.f, 0.f);
        #pragma unroll
        for (int s2 = 0; s2 < 16; ++s2) {
            const float4 v = Et[s2 * 256 + h * 32 + cc];
            s.x += v.x; s.y += v.y; s.z += v.z; s.w += v.w;
        }
        const float invl = 1.0f / lh[h];
        EbarF4[h * 32 + cc] = make_float4(s.x * invl, s.y * invl, s.z * invl, s.w * invl);
    }
    __syncthreads();

    // ---- Phase D: heads -> glimpse -> gp, 8-way k-split each ----
    {
        const int part = t >> 7, d = t & 127, h = d >> 4;
        float acc = 0.f;
        const int c0 = part * 16;
        for (int c = c0; c < c0 + 16; ++c) acc += EbarF[h * 128 + c] * Wn[c * 384 + 128 + d];
        qred[part][d] = acc;
    }
    __syncthreads();
    if (t < 128) {
        float acc = 0.f;
        #pragma unroll
        for (int p = 0; p < 8; ++p) acc += qred[p][t];
        heads[t] = acc;
    }
    __syncthreads();
    {
        const int part = t >> 7, d = t & 127;
        float acc = 0.f;
        const int j0 = part * 16;
        for (int j = j0; j < j0 + 16; ++j) acc += heads[j] * Wo[j * 128 + d];
        qred[part][d] = acc;
    }
    __syncthreads();
    if (t < 128) {
        float acc = 0.f;
        #pragma unroll
        for (int p = 0; p < 8; ++p) acc += qred[p][t];
        gl[t] = acc;
    }
    __syncthreads();
    {
        const int part = t >> 7, c = t & 127;
        float acc = 0.f;
        const int d0 = part * 16;
        for (int d = d0; d < d0 + 16; ++d) acc += Wn[c * 384 + 256 + d] * gl[d];
        qred[part][c] = acc;
    }
    __syncthreads();
    if (t < 128) {
        float acc = 0.f;
        #pragma unroll
        for (int p = 0; p < 8; ++p) acc += qred[p][t];
        gp[t] = acc * 0.08838834764831845f;   // 1/sqrt(128)
    }
    __syncthreads();

    // ---- Phase E: logits via shfl butterfly — no barriers in tile loop ----
    for (int tile = 0; tile < 8; ++tile) {
        const int g = tile * 128 + rr;
        float acc = 0.f;
        if (g < 1000) {
            #pragma unroll
            for (int i = 0; i < 4; ++i) {
                const float4 v = E4[g * 32 + qq * 4 + i];
                const float4 w = gp4[qq * 4 + i];
                acc += v.x * w.x + v.y * w.y + v.z * w.z + v.w * w.w;
            }
        }
        acc += __shfl_xor(acc, 1, 64);
        acc += __shfl_xor(acc, 2, 64);
        acc += __shfl_xor(acc, 4, 64);
        if (qq == 0 && g < 1000) {
            float zz = 10.0f * tanhf(acc);
            const bool m = useB ? (maskB[b * 1000 + g] != 0)
                                : (maskI[b * 1000 + g] != 0);
            if (m) zz = NEG;
            pt[g] = zz;
        }
    }
    __syncthreads();
    float v = (t < 1000) ? pt[t] : -3e38f;
    #pragma unroll
    for (int off = 32; off > 0; off >>= 1) v = fmaxf(v, __shfl_down(v, off, 64));
    if ((t & 63) == 0) red[t >> 6] = v;
    __syncthreads();
    if (t == 0) {
        float m = red[0];
        for (int i = 1; i < 16; ++i) m = fmaxf(m, red[i]);
        stat[0] = m;
    }
    __syncthreads();
    float sv = (t < 1000) ? __expf(pt[t] - stat[0]) : 0.f;
    #pragma unroll
    for (int off = 32; off > 0; off >>= 1) sv += __shfl_down(sv, off, 64);
    if ((t & 63) == 0) red[t >> 6] = sv;
    __syncthreads();
    if (t == 0) {
        float s = 0.f;
        for (int i = 0; i < 16; ++i) s += red[i];
        stat[1] = stat[0] + __logf(s);
    }
    __syncthreads();
    if (t < 1000)
        out[(size_t)b * 1000 + t] = pt[t] - stat[1];
}

// ---------------------------------------------------------------------------
extern "C" void kernel_launch(void* const* d_in, const int* in_sizes, int n_in,
                              void* d_out, int out_size, void* d_ws, size_t ws_size,
                              hipStream_t stream) {
    const float* E  = (const float*)d_in[0];
    const float* Wn = (const float*)d_in[1];
    const float* Wf = (const float*)d_in[2];
    const float* Ws = (const float*)d_in[3];
    const float* Wo = (const float*)d_in[4];
    const int*   fi = (const int*)d_in[5];
    const int*   li = (const int*)d_in[6];
    const int*   maskI = (const int*)d_in[7];
    const unsigned char* maskB = (const unsigned char*)d_in[7];
    float* out = (float*)d_out;

    k_fused<<<256, 1024, 0, stream>>>(E, Wn, Wf, Ws, Wo, fi, li, maskI, maskB, out);
}